// Round 1
// baseline (213.899 us; speedup 1.0000x reference)
//
#include <hip/hip_runtime.h>
#include <stdint.h>

// ---------------- types & helpers ----------------
typedef short short8 __attribute__((ext_vector_type(8)));
typedef float f32x4 __attribute__((ext_vector_type(4)));
typedef _Float16 half8 __attribute__((ext_vector_type(8)));

__device__ __forceinline__ short f2h(float f) {
    _Float16 h = (_Float16)f;
    return __builtin_bit_cast(short, h);
}

__device__ __forceinline__ f32x4 mfma16(short8 a, short8 b, f32x4 c) {
    return __builtin_amdgcn_mfma_f32_16x16x32_f16(
        __builtin_bit_cast(half8, a), __builtin_bit_cast(half8, b), c, 0, 0, 0);
}

// Problem constants: B=4, C=256, H=W=128 (PX=16384), inner=256, heads=8, c/head=32,
// patch=8 -> keys=256, conv K-dim = 256*64 = 16384.

// ---------------- pack kernels: 64x64 fp32 tile transpose -> f16 ----------------
__device__ __forceinline__ void transpose64(const float* __restrict__ src,
                                            short* __restrict__ dst,
                                            int srcSlowStride, int dstRowStride) {
    __shared__ float tile[64][65];
    const int t = threadIdx.x;
#pragma unroll
    for (int i = 0; i < 16; ++i) {
        int idx = i * 256 + t;
        int fast = idx & 63, slow = idx >> 6;
        tile[slow][fast] = src[(long)slow * srcSlowStride + fast];
    }
    __syncthreads();
#pragma unroll
    for (int i = 0; i < 2; ++i) {
        int ch = i * 256 + t;
        int fast = ch >> 3, sg = ch & 7;
        short8 v;
#pragma unroll
        for (int j = 0; j < 8; ++j) v[j] = f2h(tile[sg * 8 + j][fast]);
        *(short8*)(dst + (long)fast * dstRowStride + sg * 8) = v;
    }
}

// x: [4][256][16384] fp32 (NCHW) -> xn: [4][16384][256] f16 (NHWC)
__global__ __launch_bounds__(256) void k_pack_x(const float* __restrict__ x,
                                                short* __restrict__ xn) {
    int bi = blockIdx.x;                 // 4096 = 4b * 256pxt * 4ct
    int ct = bi & 3, pxt = (bi >> 2) & 255, b = bi >> 10;
    const float* src = x + (((long)(b * 256 + ct * 64)) << 14) + (long)pxt * 64;
    short* dst = xn + (((long)(b << 14) + pxt * 64) * 256) + ct * 64;
    transpose64(src, dst, 16384, 256);
}

// Wk/Wv: [256][256][64] fp32 -> wp: [512][64][256] f16 (oc<256: k, else v), K order (dydx, c)
__global__ __launch_bounds__(256) void k_pack_w(const float* __restrict__ wk,
                                                const float* __restrict__ wv,
                                                short* __restrict__ wp) {
    int bi = blockIdx.x;                 // 2048 = 512oc * 4ct
    int ct = bi & 3, oc = bi >> 2;
    const float* base = (oc < 256) ? (wk + (long)oc * 16384) : (wv + (long)(oc - 256) * 16384);
    const float* src = base + ct * 4096; // + c0*64
    short* dst = wp + (long)oc * 16384 + ct * 64;
    transpose64(src, dst, 64, 256);
}

// Wq: [256][256] fp32 -> f16 (layout preserved: [oc][c])
__global__ __launch_bounds__(256) void k_pack_wq(const float* __restrict__ wq,
                                                 short* __restrict__ wqp) {
    int i = blockIdx.x * 256 + threadIdx.x; // grid 256 -> 65536
    wqp[i] = f2h(wq[i]);
}

// ---------------- K/V conv as GEMM ----------------
// C[patch 1024][oc 512] = A[patch][k 16384] * B[k][oc], K-split 16 -> partials
// block: 256(M) x 128(N) x Kchunk 1024 (16 iters of BK=64), 8 waves (512 thr)
__global__ __launch_bounds__(512) void k_kv_gemm(const short* __restrict__ xn,
                                                 const short* __restrict__ wp,
                                                 float* __restrict__ part) {
    __shared__ short Al[256 * 64]; // rows 128B = 8 granules, swizzled
    __shared__ short Bl[128 * 64];
    int bid = blockIdx.x;                       // 256
    int wg = (bid & 7) * 32 + (bid >> 3);       // XCD-contiguous swizzle (256 = 8*32)
    int nb = wg & 3, pm = (wg >> 2) & 3, kc = wg >> 4;
    int t = threadIdx.x, l = t & 63, w = t >> 6;
    int wm = w >> 1, wn = w & 1;

    f32x4 acc[4][4];
#pragma unroll
    for (int mt = 0; mt < 4; ++mt)
#pragma unroll
        for (int nt = 0; nt < 4; ++nt) acc[mt][nt] = (f32x4){0.f, 0.f, 0.f, 0.f};

    for (int kk = 0; kk < 16; ++kk) {
        short8 va[4], vb[2];
#pragma unroll
        for (int i = 0; i < 4; ++i) {           // A: 2048 granules
            int g = i * 512 + t;
            int row = g >> 3, lg = g & 7;
            int patch = pm * 256 + row;
            int kg = kc * 1024 + kk * 64 + lg * 8;
            int dydx = kg >> 8, cc = kg & 255;
            int bb = patch >> 8, pid = patch & 255;
            int ph = pid >> 4, pw = pid & 15;
            int px = (ph * 8 + (dydx >> 3)) * 128 + pw * 8 + (dydx & 7);
            va[i] = *(const short8*)(xn + ((long)(bb << 14) + px) * 256 + cc);
        }
#pragma unroll
        for (int i = 0; i < 2; ++i) {           // B: 1024 granules
            int g = i * 512 + t;
            int row = g >> 3, lg = g & 7;
            int oc = nb * 128 + row;
            int kg = kc * 1024 + kk * 64 + lg * 8;
            vb[i] = *(const short8*)(wp + (long)oc * 16384 + kg);
        }
#pragma unroll
        for (int i = 0; i < 4; ++i) {
            int g = i * 512 + t;
            int row = g >> 3, lg = g & 7;
            *(short8*)(Al + row * 64 + ((lg ^ (row & 7)) * 8)) = va[i];
        }
#pragma unroll
        for (int i = 0; i < 2; ++i) {
            int g = i * 512 + t;
            int row = g >> 3, lg = g & 7;
            *(short8*)(Bl + row * 64 + ((lg ^ (row & 7)) * 8)) = vb[i];
        }
        __syncthreads();
#pragma unroll
        for (int ks = 0; ks < 2; ++ks) {
            short8 af[4], bf[4];
#pragma unroll
            for (int mt = 0; mt < 4; ++mt) {
                int row = wm * 64 + mt * 16 + (l & 15);
                int lg = ks * 4 + (l >> 4);
                af[mt] = *(const short8*)(Al + row * 64 + ((lg ^ (row & 7)) * 8));
            }
#pragma unroll
            for (int nt = 0; nt < 4; ++nt) {
                int row = wn * 64 + nt * 16 + (l & 15);
                int lg = ks * 4 + (l >> 4);
                bf[nt] = *(const short8*)(Bl + row * 64 + ((lg ^ (row & 7)) * 8));
            }
#pragma unroll
            for (int mt = 0; mt < 4; ++mt)
#pragma unroll
                for (int nt = 0; nt < 4; ++nt)
                    acc[mt][nt] = mfma16(af[mt], bf[nt], acc[mt][nt]);
        }
        __syncthreads();
    }
    // D: row(patch) = (l>>4)*4+r (+16mt+64wm+256pm), col(oc) = (l&15) (+16nt+64wn+128nb)
#pragma unroll
    for (int mt = 0; mt < 4; ++mt) {
        int patch = pm * 256 + wm * 64 + mt * 16 + ((l >> 4) * 4);
#pragma unroll
        for (int nt = 0; nt < 4; ++nt) {
            int oc = nb * 128 + wn * 64 + nt * 16 + (l & 15);
#pragma unroll
            for (int r = 0; r < 4; ++r)
                part[((long)kc * 1024 + patch + r) * 512 + oc] = acc[mt][nt][r];
        }
    }
}

// reduce partials, add bias, pack k -> [b][h][key][c], v -> [b][h][c][key] (f16)
__global__ __launch_bounds__(256) void k_kv_fin(const float* __restrict__ part,
                                                const float* __restrict__ bk,
                                                const float* __restrict__ bv,
                                                short* __restrict__ kp,
                                                short* __restrict__ vp) {
    int idx = blockIdx.x * 256 + threadIdx.x;   // 524288 = 1024patch * 512oc
    int oc = idx & 511, patch = idx >> 9;
    float s = 0.f;
#pragma unroll
    for (int kc = 0; kc < 16; ++kc) s += part[(long)kc * 524288 + idx];
    int b = patch >> 8, key = patch & 255;
    if (oc < 256) {
        s += bk[oc];
        kp[(((long)(b * 8 + (oc & 7)) * 256) + key) * 32 + (oc >> 3)] = f2h(s);
    } else {
        int o = oc - 256;
        s += bv[o];
        vp[(((long)(b * 8 + (o & 7)) * 32) + (o >> 3)) * 256 + key] = f2h(s);
    }
}

// ---------------- Q conv (1x1) as GEMM ----------------
// D[oc 256][px 128] per block; q out layout [b][h 8][c 32][px 16384] f16
__global__ __launch_bounds__(256) void k_q_gemm(const short* __restrict__ xn,
                                                const short* __restrict__ wqp,
                                                const float* __restrict__ bq,
                                                short* __restrict__ qp) {
    __shared__ short Xl[128 * 256]; // [px][c], rows 512B = 32 granules, swizzled
    int bi = blockIdx.x;            // 512 = 4b * 128tiles
    int b = bi >> 7, tile = bi & 127;
    long px0 = (long)tile * 128;
    int t = threadIdx.x, l = t & 63, w = t >> 6;
#pragma unroll
    for (int i = 0; i < 16; ++i) {
        int g = i * 256 + t;        // 4096 granules
        int px = g >> 5, lg = g & 31;
        short8 v = *(const short8*)(xn + (((long)(b << 14)) + px0 + px) * 256 + lg * 8);
        *(short8*)(Xl + px * 256 + ((lg ^ (px & 7)) * 8)) = v;
    }
    __syncthreads();

    f32x4 acc[16][2];
#pragma unroll
    for (int mt = 0; mt < 16; ++mt) {
        acc[mt][0] = (f32x4){0.f, 0.f, 0.f, 0.f};
        acc[mt][1] = (f32x4){0.f, 0.f, 0.f, 0.f};
    }
#pragma unroll
    for (int kstep = 0; kstep < 8; ++kstep) {
        short8 bf[2];
#pragma unroll
        for (int nt = 0; nt < 2; ++nt) {
            int px = w * 32 + nt * 16 + (l & 15);
            int lg = kstep * 4 + (l >> 4);
            bf[nt] = *(const short8*)(Xl + px * 256 + ((lg ^ (px & 7)) * 8));
        }
#pragma unroll
        for (int mt = 0; mt < 16; ++mt) {
            short8 af = *(const short8*)(wqp + (mt * 16 + (l & 15)) * 256 + kstep * 32 + (l >> 4) * 8);
#pragma unroll
            for (int nt = 0; nt < 2; ++nt)
                acc[mt][nt] = mfma16(af, bf[nt], acc[mt][nt]);
        }
    }
    // D: row(oc) = (l>>4)*4+r+16mt, col(px) = (l&15)+16nt+32w -> write [b][h][c][px]
#pragma unroll
    for (int mt = 0; mt < 16; ++mt)
#pragma unroll
        for (int nt = 0; nt < 2; ++nt)
#pragma unroll
            for (int r = 0; r < 4; ++r) {
                int oc = mt * 16 + (l >> 4) * 4 + r;
                long px = px0 + w * 32 + nt * 16 + (l & 15);
                float v = acc[mt][nt][r] + bq[oc];
                qp[((long)((b * 8 + (oc & 7)) * 32 + (oc >> 3))) * 16384 + px] = f2h(v);
            }
}

// ---------------- fused attention ----------------
// per block: 128 px, all 8 heads. dots computed transposed: D[key][px] = K * q
__global__ __launch_bounds__(256) void k_attn(const short* __restrict__ qp,
                                              const short* __restrict__ kp,
                                              const short* __restrict__ vp,
                                              float* __restrict__ out) {
    __shared__ short Kl[256 * 32];   // [key][c], rows 64B = 4 granules, swizzled
    __shared__ short Vl[32 * 256];   // [c][key], rows 512B = 32 granules, swizzled
    __shared__ short Pl[4][32 * 32]; // per-wave P chunk [px][key32], rows 64B
    int bi = blockIdx.x;             // 512 = 4b * 128tiles
    int b = bi >> 7, tile = bi & 127;
    long px0 = (long)tile * 128;
    int t = threadIdx.x, l = t & 63, w = t >> 6;

#pragma unroll 1
    for (int h = 0; h < 8; ++h) {
        if (h) __syncthreads();
        // stage K [256][32]
#pragma unroll
        for (int i = 0; i < 4; ++i) {
            int g = i * 256 + t;
            int key = g >> 2, lg = g & 3;
            short8 v = *(const short8*)(kp + (((long)(b * 8 + h) * 256) + key) * 32 + lg * 8);
            *(short8*)(Kl + key * 32 + ((lg ^ (key & 3)) * 8)) = v;
        }
        // stage V [32][256]
#pragma unroll
        for (int i = 0; i < 4; ++i) {
            int g = i * 256 + t;
            int c = g >> 5, lg = g & 31;
            short8 v = *(const short8*)(vp + (((long)(b * 8 + h) * 32) + c) * 256 + lg * 8);
            *(short8*)(Vl + c * 256 + ((lg ^ (c & 7)) * 8)) = v;
        }
        __syncthreads();
        // q B-fragments (global, [b][h][c][px]): n=px=(l&15)+16nt+32w, k=c=(l>>4)*8+j
        short8 bq2[2];
#pragma unroll
        for (int nt = 0; nt < 2; ++nt) {
            long px = px0 + w * 32 + nt * 16 + (l & 15);
            int c0 = (l >> 4) * 8;
            const short* q = qp + ((long)((b * 8 + h) * 32 + c0)) * 16384 + px;
#pragma unroll
            for (int j = 0; j < 8; ++j) bq2[nt][j] = q[(long)j * 16384];
        }
        // dots^T: D[key 256][px 32]
        f32x4 d[16][2];
#pragma unroll
        for (int mt = 0; mt < 16; ++mt) {
            d[mt][0] = (f32x4){0.f, 0.f, 0.f, 0.f};
            d[mt][1] = (f32x4){0.f, 0.f, 0.f, 0.f};
        }
#pragma unroll
        for (int mt = 0; mt < 16; ++mt) {
            int key = mt * 16 + (l & 15);
            int lg = l >> 4;
            short8 ak = *(const short8*)(Kl + key * 32 + ((lg ^ (key & 3)) * 8));
            d[mt][0] = mfma16(ak, bq2[0], d[mt][0]);
            d[mt][1] = mfma16(ak, bq2[1], d[mt][1]);
        }
        // softmax over keys: per lane 64 values + shfl over lane bits 4,5
        float inv[2];
#pragma unroll
        for (int nt = 0; nt < 2; ++nt) {
            float m = -1e30f;
#pragma unroll
            for (int mt = 0; mt < 16; ++mt)
#pragma unroll
                for (int r = 0; r < 4; ++r) m = fmaxf(m, d[mt][nt][r]);
            m = fmaxf(m, __shfl_xor(m, 16));
            m = fmaxf(m, __shfl_xor(m, 32));
            float s = 0.f;
#pragma unroll
            for (int mt = 0; mt < 16; ++mt)
#pragma unroll
                for (int r = 0; r < 4; ++r) {
                    float p = __expf(d[mt][nt][r] - m);
                    d[mt][nt][r] = p;
                    s += p;
                }
            s += __shfl_xor(s, 16);
            s += __shfl_xor(s, 32);
            inv[nt] = 1.0f / s;
        }
        // PV: out^T[c 32][px 32] accumulated over 8 chunks of 32 keys
        f32x4 o2[2][2];
        o2[0][0] = (f32x4){0.f, 0.f, 0.f, 0.f};
        o2[0][1] = (f32x4){0.f, 0.f, 0.f, 0.f};
        o2[1][0] = (f32x4){0.f, 0.f, 0.f, 0.f};
        o2[1][1] = (f32x4){0.f, 0.f, 0.f, 0.f};
#pragma unroll
        for (int kc2 = 0; kc2 < 8; ++kc2) {
            // write P chunk (wave-local LDS, same-wave read below)
#pragma unroll
            for (int nt = 0; nt < 2; ++nt) {
                int pxl = nt * 16 + (l & 15);
#pragma unroll
                for (int mh = 0; mh < 2; ++mh) {
                    int mt = kc2 * 2 + mh;
#pragma unroll
                    for (int r = 0; r < 4; ++r) {
                        int kl = mh * 16 + (l >> 4) * 4 + r;
                        Pl[w][pxl * 32 + (((kl >> 3) ^ (pxl & 3)) * 8) + (kl & 7)] =
                            f2h(d[mt][nt][r]);
                    }
                }
            }
            short8 av[2], bp[2];
#pragma unroll
            for (int ct = 0; ct < 2; ++ct) {
                int c = ct * 16 + (l & 15);
                int lg = kc2 * 4 + (l >> 4);
                av[ct] = *(const short8*)(Vl + c * 256 + ((lg ^ (c & 7)) * 8));
            }
#pragma unroll
            for (int nt = 0; nt < 2; ++nt) {
                int pxl = nt * 16 + (l & 15);
                bp[nt] = *(const short8*)(Pl[w] + pxl * 32 + (((l >> 4) ^ (pxl & 3)) * 8));
            }
#pragma unroll
            for (int ct = 0; ct < 2; ++ct)
#pragma unroll
                for (int nt = 0; nt < 2; ++nt)
                    o2[ct][nt] = mfma16(av[ct], bp[nt], o2[ct][nt]);
        }
        // write out [b][c*8+h][px] fp32
#pragma unroll
        for (int ct = 0; ct < 2; ++ct)
#pragma unroll
            for (int nt = 0; nt < 2; ++nt)
#pragma unroll
                for (int r = 0; r < 4; ++r) {
                    int c = ct * 16 + (l >> 4) * 4 + r;
                    int ch = c * 8 + h;
                    out[(((long)(b * 256 + ch)) << 14) + px0 + w * 32 + nt * 16 + (l & 15)] =
                        o2[ct][nt][r] * inv[nt];
                }
    }
}

// ---------------- launch ----------------
extern "C" void kernel_launch(void* const* d_in, const int* in_sizes, int n_in,
                              void* d_out, int out_size, void* d_ws, size_t ws_size,
                              hipStream_t stream) {
    const float* x  = (const float*)d_in[0];
    const float* Wq = (const float*)d_in[1];
    const float* bq = (const float*)d_in[2];
    const float* Wk = (const float*)d_in[3];
    const float* bk = (const float*)d_in[4];
    const float* Wv = (const float*)d_in[5];
    const float* bv = (const float*)d_in[6];
    float* out = (float*)d_out;

    char* ws = (char*)d_ws;
    const size_t OFF_XN = 0;             // 33,554,432  x NHWC f16
    const size_t OFF_Q  = 33554432;      // 33,554,432  q [b][h][c][px] f16
    const size_t OFF_WP = 67108864;      // 16,777,216  w_pack [512][16384] f16
    const size_t OFF_WQ = 83886080;      //    131,072  wq f16
    const size_t OFF_KP = 84017152;      //    524,288  k_pack f16
    const size_t OFF_VP = 84541440;      //    524,288  v_pack f16
    const size_t OFF_PT = 85065728;      // 33,554,432  partials fp32 [16][1024][512]
    const size_t NEEDED = 118620160;
    if (ws_size < NEEDED) return;        // fail loudly via validation

    short* xn  = (short*)(ws + OFF_XN);
    short* qp  = (short*)(ws + OFF_Q);
    short* wp  = (short*)(ws + OFF_WP);
    short* wqp = (short*)(ws + OFF_WQ);
    short* kp  = (short*)(ws + OFF_KP);
    short* vp  = (short*)(ws + OFF_VP);
    float* part= (float*)(ws + OFF_PT);

    k_pack_x <<<dim3(4096), dim3(256), 0, stream>>>(x, xn);
    k_pack_w <<<dim3(2048), dim3(256), 0, stream>>>(Wk, Wv, wp);
    k_pack_wq<<<dim3(256),  dim3(256), 0, stream>>>(Wq, wqp);
    k_kv_gemm<<<dim3(256),  dim3(512), 0, stream>>>(xn, wp, part);
    k_kv_fin <<<dim3(2048), dim3(256), 0, stream>>>(part, bk, bv, kp, vp);
    k_q_gemm <<<dim3(512),  dim3(256), 0, stream>>>(xn, wqp, bq, qp);
    k_attn   <<<dim3(512),  dim3(256), 0, stream>>>(qp, kp, vp, out);
}